// Round 1
// baseline (1006.156 us; speedup 1.0000x reference)
//
#include <hip/hip_runtime.h>
#include <hip/hip_bf16.h>
#include <cstdint>
#include <cstddef>

#define B_DIM 64
#define K_DIM 2048
#define D_DIM 32400

typedef __bf16 bf16x8 __attribute__((ext_vector_type(8)));
typedef float f32x4 __attribute__((ext_vector_type(4)));

struct F8 { float v[8]; };

// Load 8 consecutive floats with zero-fill guard at dlim. Alignment: callers
// guarantee (row_start + d) is a multiple of 4 floats (16B).
__device__ inline F8 ld8g(const float* __restrict__ base, int d, int dlim) {
    F8 r;
    if (d + 8 <= dlim) {
        const float4 a = *reinterpret_cast<const float4*>(base + d);
        const float4 b = *reinterpret_cast<const float4*>(base + d + 4);
        r.v[0] = a.x; r.v[1] = a.y; r.v[2] = a.z; r.v[3] = a.w;
        r.v[4] = b.x; r.v[5] = b.y; r.v[6] = b.z; r.v[7] = b.w;
    } else {
        #pragma unroll
        for (int j = 0; j < 8; ++j) r.v[j] = (d + j < dlim) ? base[d + j] : 0.0f;
    }
    return r;
}

__device__ inline bf16x8 cvt8(const F8& f) {
    bf16x8 o;
    #pragma unroll
    for (int j = 0; j < 8; ++j) o[j] = (__bf16)f.v[j];
    return o;
}

__device__ inline bf16x8 cvt8n(const F8& f) {  // negated
    bf16x8 o;
    #pragma unroll
    for (int j = 0; j < 8; ++j) o[j] = (__bf16)(-f.v[j]);
    return o;
}

__device__ inline f32x4 mfma16(bf16x8 a, bf16x8 b, f32x4 c) {
    return __builtin_amdgcn_mfma_f32_16x16x32_bf16(a, b, c, 0, 0, 0);
}

// Phase 1: coeffs[b,k] = (sum_d X[b,d] * conj(bases[k,d])) * w[k]
// Split-D partial sums atomically accumulated into ws (w-scaling is linear,
// so it can be applied per-partial before the atomicAdd).
__global__ __launch_bounds__(256) void p1_coeffs(
    const float* __restrict__ Xre, const float* __restrict__ Xim,
    const float* __restrict__ Bre, const float* __restrict__ Bim,
    const float* __restrict__ Wre, const float* __restrict__ Wim,
    float* __restrict__ Cre, float* __restrict__ Cim)
{
    const int kt = blockIdx.x;        // 32 k-tiles of 64 basis columns
    const int dc = blockIdx.y;        // 16 d-chunks of 2048
    const int tid  = threadIdx.x;
    const int lane = tid & 63;
    const int w    = tid >> 6;        // 4 waves: 2x2 quadrants of the 64x64 tile
    const int r    = lane & 15;
    const int g    = lane >> 4;

    const int n0b    = kt * 64;
    const int dstart = dc * 2048;
    const int dend   = min(dstart + 2048, D_DIM);
    const int nsteps = (dend - dstart + 31) >> 5;

    const int m0 = (w & 1) * 32;
    const int n0 = n0b + (w >> 1) * 32;

    f32x4 accRe[2][2] = {};
    f32x4 accIm[2][2] = {};

    const int dg = g * 8;
    for (int s = 0; s < nsteps; ++s) {
        const int dk = dstart + s * 32 + dg;   // this lane's k-dim (d) offset
        bf16x8 aRe[2], aIm[2], aReN[2], bReF[2], bImF[2];
        #pragma unroll
        for (int ms = 0; ms < 2; ++ms) {
            const size_t row = (size_t)(m0 + ms * 16 + r) * D_DIM;
            F8 fre = ld8g(Xre + row, dk, dend);
            F8 fim = ld8g(Xim + row, dk, dend);
            aRe[ms]  = cvt8(fre);
            aIm[ms]  = cvt8(fim);
            aReN[ms] = cvt8n(fre);
        }
        #pragma unroll
        for (int ns = 0; ns < 2; ++ns) {
            const size_t row = (size_t)(n0 + ns * 16 + r) * D_DIM;
            bReF[ns] = cvt8(ld8g(Bre + row, dk, dend));
            bImF[ns] = cvt8(ld8g(Bim + row, dk, dend));
        }
        #pragma unroll
        for (int ms = 0; ms < 2; ++ms)
        #pragma unroll
        for (int ns = 0; ns < 2; ++ns) {
            // C_re += Xre*Bre + Xim*Bim ; C_im += Xim*Bre - Xre*Bim
            accRe[ms][ns] = mfma16(aRe[ms],  bReF[ns], accRe[ms][ns]);
            accRe[ms][ns] = mfma16(aIm[ms],  bImF[ns], accRe[ms][ns]);
            accIm[ms][ns] = mfma16(aIm[ms],  bReF[ns], accIm[ms][ns]);
            accIm[ms][ns] = mfma16(aReN[ms], bImF[ns], accIm[ms][ns]);
        }
    }

    // Epilogue: scale by w[k] (complex) and atomically accumulate.
    // C/D layout (m89-verified): col = lane&15, row = (lane>>4)*4 + reg.
    #pragma unroll
    for (int ms = 0; ms < 2; ++ms)
    #pragma unroll
    for (int ns = 0; ns < 2; ++ns) {
        const int kb  = n0 + ns * 16 + r;
        const float wre = Wre[kb], wim = Wim[kb];
        #pragma unroll
        for (int i = 0; i < 4; ++i) {
            const int b = m0 + ms * 16 + g * 4 + i;
            const float cre = accRe[ms][ns][i];
            const float cim = accIm[ms][ns][i];
            atomicAdd(&Cre[b * K_DIM + kb], cre * wre - cim * wim);
            atomicAdd(&Cim[b * K_DIM + kb], cre * wim + cim * wre);
        }
    }
}

// Phase 2: out[b,d] = sum_k c[b,k] * bases[k,d]  (complex mult; real part
// always, imaginary part only when out_size == 2*B*D).
template <bool WIM>
__global__ __launch_bounds__(256) void p2_project(
    const float* __restrict__ Bre, const float* __restrict__ Bim,
    const float* __restrict__ Cre, const float* __restrict__ Cim,
    float* __restrict__ out)
{
    const int dt   = blockIdx.x;      // d-tile of 64 columns
    const int tid  = threadIdx.x;
    const int lane = tid & 63;
    const int w    = tid >> 6;
    const int r    = lane & 15;
    const int g    = lane >> 4;

    const int m0 = (w & 1) * 32;
    const int d0 = dt * 64 + (w >> 1) * 32;

    f32x4 accRe[2][2] = {};
    f32x4 accIm[2][2] = {};

    for (int k0 = 0; k0 < K_DIM; k0 += 32) {
        const int kb = k0 + g * 8;    // this lane's k-dim (basis) offset
        bf16x8 aCre[2], aCim[2], aCimN[2], bReF[2], bImF[2];
        #pragma unroll
        for (int ms = 0; ms < 2; ++ms) {
            const int b = m0 + ms * 16 + r;
            F8 fre = ld8g(Cre + (size_t)b * K_DIM, kb, K_DIM);
            F8 fim = ld8g(Cim + (size_t)b * K_DIM, kb, K_DIM);
            aCre[ms]  = cvt8(fre);
            aCimN[ms] = cvt8n(fim);
            if (WIM) aCim[ms] = cvt8(fim);
        }
        #pragma unroll
        for (int ns = 0; ns < 2; ++ns) {
            const int d = d0 + ns * 16 + r;
            const bool ok = d < D_DIM;
            F8 fre, fim;
            const float* pre = Bre + (size_t)kb * D_DIM + d;
            const float* pim = Bim + (size_t)kb * D_DIM + d;
            #pragma unroll
            for (int j = 0; j < 8; ++j) {
                fre.v[j] = ok ? pre[(size_t)j * D_DIM] : 0.0f;
                fim.v[j] = ok ? pim[(size_t)j * D_DIM] : 0.0f;
            }
            bReF[ns] = cvt8(fre);
            bImF[ns] = cvt8(fim);
        }
        #pragma unroll
        for (int ms = 0; ms < 2; ++ms)
        #pragma unroll
        for (int ns = 0; ns < 2; ++ns) {
            // out_re += cre*Bre - cim*Bim ; out_im += cre*Bim + cim*Bre
            accRe[ms][ns] = mfma16(aCre[ms],  bReF[ns], accRe[ms][ns]);
            accRe[ms][ns] = mfma16(aCimN[ms], bImF[ns], accRe[ms][ns]);
            if (WIM) {
                accIm[ms][ns] = mfma16(aCre[ms], bImF[ns], accIm[ms][ns]);
                accIm[ms][ns] = mfma16(aCim[ms], bReF[ns], accIm[ms][ns]);
            }
        }
    }

    #pragma unroll
    for (int ms = 0; ms < 2; ++ms)
    #pragma unroll
    for (int ns = 0; ns < 2; ++ns) {
        const int d = d0 + ns * 16 + r;
        if (d < D_DIM) {
            #pragma unroll
            for (int i = 0; i < 4; ++i) {
                const int b = m0 + ms * 16 + g * 4 + i;
                if (!WIM) {
                    out[(size_t)b * D_DIM + d] = accRe[ms][ns][i];
                } else {
                    out[((size_t)b * D_DIM + d) * 2]     = accRe[ms][ns][i];
                    out[((size_t)b * D_DIM + d) * 2 + 1] = accIm[ms][ns][i];
                }
            }
        }
    }
}

extern "C" void kernel_launch(void* const* d_in, const int* in_sizes, int n_in,
                              void* d_out, int out_size, void* d_ws, size_t ws_size,
                              hipStream_t stream) {
    const float* Xre = (const float*)d_in[0];
    const float* Xim = (const float*)d_in[1];
    const float* Bre = (const float*)d_in[2];
    const float* Bim = (const float*)d_in[3];
    const float* Wre = (const float*)d_in[4];
    const float* Wim = (const float*)d_in[5];

    float* Cre = (float*)d_ws;                 // [64][2048] f32
    float* Cim = Cre + B_DIM * K_DIM;          // [64][2048] f32

    (void)hipMemsetAsync(d_ws, 0, (size_t)2 * B_DIM * K_DIM * sizeof(float), stream);

    dim3 g1(32, 16);
    p1_coeffs<<<g1, 256, 0, stream>>>(Xre, Xim, Bre, Bim, Wre, Wim, Cre, Cim);

    const int ndt = (D_DIM + 63) / 64;  // 507
    if (out_size == 2 * B_DIM * D_DIM) {
        p2_project<true><<<ndt, 256, 0, stream>>>(Bre, Bim, Cre, Cim, (float*)d_out);
    } else {
        p2_project<false><<<ndt, 256, 0, stream>>>(Bre, Bim, Cre, Cim, (float*)d_out);
    }
}

// Round 2
// 386.563 us; speedup vs baseline: 2.6028x; 2.6028x over previous
//
#include <hip/hip_runtime.h>
#include <hip/hip_bf16.h>
#include <cstdint>
#include <cstddef>

#define B_DIM 64
#define K_DIM 2048
#define D_DIM 32400

typedef __bf16 bf16x8 __attribute__((ext_vector_type(8)));
typedef float f32x4 __attribute__((ext_vector_type(4)));

union U128 { uint4 u; bf16x8 b; };

__device__ inline bf16x8 asbf(uint4 u) { U128 x; x.u = u; return x.b; }

__device__ inline uint4 neg4(uint4 u) {
    u.x ^= 0x80008000u; u.y ^= 0x80008000u; u.z ^= 0x80008000u; u.w ^= 0x80008000u;
    return u;
}

__device__ inline f32x4 mfma16(bf16x8 a, bf16x8 b, f32x4 c) {
    return __builtin_amdgcn_mfma_f32_16x16x32_bf16(a, b, c, 0, 0, 0);
}

// guarded float4 load: element index d within row pointer p, limit dlim
__device__ inline f32x4 ld4g(const float* __restrict__ p, int d, int dlim) {
    f32x4 r;
    if (d + 4 <= dlim) {
        float4 v = *reinterpret_cast<const float4*>(p + d);
        r[0] = v.x; r[1] = v.y; r[2] = v.z; r[3] = v.w;
    } else {
        #pragma unroll
        for (int j = 0; j < 4; ++j) r[j] = (d + j < dlim) ? p[d + j] : 0.0f;
    }
    return r;
}

// pack two floats -> dword of 2 bf16 (lo = a, hi = b)
__device__ inline uint32_t pk(float a, float b) {
    union { __bf16 h[2]; uint32_t u; } x;
    x.h[0] = (__bf16)a; x.h[1] = (__bf16)b;
    return x.u;
}

// ---------------------------------------------------------------------------
// Phase 1: coeffs[b,k] = (sum_d X[b,d]*conj(bases[k,d])) * w[k], split-D atomic
// Staged LDS GEMM: tiles [64 rows][32 d] of X and bases as bf16, double-buffered
// ---------------------------------------------------------------------------
#define P1_STRIDE 40  // 32 d + 8 pad (80B rows: 16B aligned, spreads banks)

__global__ __launch_bounds__(256) void p1_coeffs(
    const float* __restrict__ Xre, const float* __restrict__ Xim,
    const float* __restrict__ Bre, const float* __restrict__ Bim,
    const float* __restrict__ Wre, const float* __restrict__ Wim,
    float* __restrict__ Cre, float* __restrict__ Cim)
{
    __shared__ __align__(16) __bf16 sX[2][2][64][P1_STRIDE];
    __shared__ __align__(16) __bf16 sB[2][2][64][P1_STRIDE];

    const int kt = blockIdx.x;        // 32 k-tiles of 64
    const int dc = blockIdx.y;        // 32 d-chunks of 1024
    const int tid  = threadIdx.x;
    const int lane = tid & 63;
    const int w    = tid >> 6;
    const int r    = lane & 15;
    const int g    = lane >> 4;

    const int kbase  = kt * 64;
    const int dstart = dc * 1024;
    const int dend   = min(dstart + 1024, D_DIM);
    const int nsteps = (dend - dstart + 31) >> 5;

    // staging map: thread handles rows (tid>>3) and (tid>>3)+32 at d=(tid&7)*4
    const int srow = tid >> 3;          // 0..31
    const int sd   = (tid & 7) * 4;     // 0..28

    const size_t xo0 = (size_t)srow * D_DIM;
    const size_t xo1 = (size_t)(srow + 32) * D_DIM;
    const size_t bo0 = (size_t)(kbase + srow) * D_DIM;
    const size_t bo1 = (size_t)(kbase + srow + 32) * D_DIM;

    f32x4 st[8];

    auto LOADS = [&](int s) {
        const int dg = dstart + s * 32 + sd;
        st[0] = ld4g(Xre + xo0, dg, dend);
        st[1] = ld4g(Xre + xo1, dg, dend);
        st[2] = ld4g(Xim + xo0, dg, dend);
        st[3] = ld4g(Xim + xo1, dg, dend);
        st[4] = ld4g(Bre + bo0, dg, dend);
        st[5] = ld4g(Bre + bo1, dg, dend);
        st[6] = ld4g(Bim + bo0, dg, dend);
        st[7] = ld4g(Bim + bo1, dg, dend);
    };

    auto WRITE = [&](int buf) {
        *(uint2*)&sX[buf][0][srow][sd]      = make_uint2(pk(st[0][0], st[0][1]), pk(st[0][2], st[0][3]));
        *(uint2*)&sX[buf][0][srow + 32][sd] = make_uint2(pk(st[1][0], st[1][1]), pk(st[1][2], st[1][3]));
        *(uint2*)&sX[buf][1][srow][sd]      = make_uint2(pk(st[2][0], st[2][1]), pk(st[2][2], st[2][3]));
        *(uint2*)&sX[buf][1][srow + 32][sd] = make_uint2(pk(st[3][0], st[3][1]), pk(st[3][2], st[3][3]));
        *(uint2*)&sB[buf][0][srow][sd]      = make_uint2(pk(st[4][0], st[4][1]), pk(st[4][2], st[4][3]));
        *(uint2*)&sB[buf][0][srow + 32][sd] = make_uint2(pk(st[5][0], st[5][1]), pk(st[5][2], st[5][3]));
        *(uint2*)&sB[buf][1][srow][sd]      = make_uint2(pk(st[6][0], st[6][1]), pk(st[6][2], st[6][3]));
        *(uint2*)&sB[buf][1][srow + 32][sd] = make_uint2(pk(st[7][0], st[7][1]), pk(st[7][2], st[7][3]));
    };

    const int m0  = (w & 1) * 32;     // local b quadrant
    const int nl0 = (w >> 1) * 32;    // local k quadrant

    f32x4 accRe[2][2] = {};
    f32x4 accIm[2][2] = {};

    auto COMPUTE = [&](int buf) {
        uint4 xre[2], xim[2], bre[2], bim[2];
        #pragma unroll
        for (int ms = 0; ms < 2; ++ms) {
            xre[ms] = *(const uint4*)&sX[buf][0][m0 + ms * 16 + r][g * 8];
            xim[ms] = *(const uint4*)&sX[buf][1][m0 + ms * 16 + r][g * 8];
        }
        #pragma unroll
        for (int ns = 0; ns < 2; ++ns) {
            bre[ns] = *(const uint4*)&sB[buf][0][nl0 + ns * 16 + r][g * 8];
            bim[ns] = *(const uint4*)&sB[buf][1][nl0 + ns * 16 + r][g * 8];
        }
        #pragma unroll
        for (int ms = 0; ms < 2; ++ms)
        #pragma unroll
        for (int ns = 0; ns < 2; ++ns) {
            // C_re += Xre*Bre + Xim*Bim ; C_im += Xim*Bre - Xre*Bim
            accRe[ms][ns] = mfma16(asbf(xre[ms]), asbf(bre[ns]), accRe[ms][ns]);
            accRe[ms][ns] = mfma16(asbf(xim[ms]), asbf(bim[ns]), accRe[ms][ns]);
            accIm[ms][ns] = mfma16(asbf(xim[ms]), asbf(bre[ns]), accIm[ms][ns]);
            accIm[ms][ns] = mfma16(asbf(neg4(xre[ms])), asbf(bim[ns]), accIm[ms][ns]);
        }
    };

    LOADS(0); WRITE(0); __syncthreads();
    for (int s = 0; s < nsteps; ++s) {
        if (s + 1 < nsteps) LOADS(s + 1);
        COMPUTE(s & 1);
        if (s + 1 < nsteps) WRITE((s + 1) & 1);
        __syncthreads();
    }

    // epilogue: scale by w[k], atomic accumulate (C/D: col=lane&15, row=g*4+i)
    #pragma unroll
    for (int ms = 0; ms < 2; ++ms)
    #pragma unroll
    for (int ns = 0; ns < 2; ++ns) {
        const int kb = kbase + nl0 + ns * 16 + r;
        const float wre = Wre[kb], wim = Wim[kb];
        #pragma unroll
        for (int i = 0; i < 4; ++i) {
            const int b = m0 + ms * 16 + g * 4 + i;
            const float cre = accRe[ms][ns][i];
            const float cim = accIm[ms][ns][i];
            atomicAdd(&Cre[b * K_DIM + kb], cre * wre - cim * wim);
            atomicAdd(&Cim[b * K_DIM + kb], cre * wim + cim * wre);
        }
    }
}

// ---------------------------------------------------------------------------
// Phase 1.5: coeffs f32 -> bf16
// ---------------------------------------------------------------------------
__global__ __launch_bounds__(256) void cbf_kernel(
    const float* __restrict__ Cre, const float* __restrict__ Cim,
    __bf16* __restrict__ CreBf, __bf16* __restrict__ CimBf)
{
    const int i = blockIdx.x * 256 + threadIdx.x;
    if (i < B_DIM * K_DIM) {
        CreBf[i] = (__bf16)Cre[i];
        CimBf[i] = (__bf16)Cim[i];
    }
}

// ---------------------------------------------------------------------------
// Phase 2: out[b,d] = sum_k coeffs[b,k] * bases[k,d]
// bases tile [64 k][64 d] staged TRANSPOSED into LDS [d][k] (bf16), so the
// k-major B-fragment is one ds_read_b128. A-fragment = bf16 coeffs from L2.
// ---------------------------------------------------------------------------
#define P2_STRIDE 72  // 64 k + 8 pad (144B rows, 16B aligned)

template <bool WIM>
__global__ __launch_bounds__(256) void p2_project(
    const float* __restrict__ Bre, const float* __restrict__ Bim,
    const __bf16* __restrict__ CreBf, const __bf16* __restrict__ CimBf,
    float* __restrict__ out)
{
    __shared__ __align__(16) __bf16 sT[2][2][64][P2_STRIDE];  // [buf][mat][d][k]

    const int dt = blockIdx.x;
    const int d0 = dt * 64;
    const int tid  = threadIdx.x;
    const int lane = tid & 63;
    const int w    = tid >> 6;
    const int r    = lane & 15;
    const int g    = lane >> 4;

    // staging map: thread t handles k-rows 4*(t>>4)..+3 at d = (t&15)*4
    const int kq = tid >> 4;          // 0..15
    const int ds = (tid & 15) * 4;    // 0..60

    f32x4 st[8];  // 4 k-rows x {re, im}

    auto LOADS = [&](int t) {
        const int k0 = t * 64;
        #pragma unroll
        for (int j = 0; j < 4; ++j) {
            const size_t ro = (size_t)(k0 + kq * 4 + j) * D_DIM;
            st[j]     = ld4g(Bre + ro, d0 + ds, D_DIM);
            st[4 + j] = ld4g(Bim + ro, d0 + ds, D_DIM);
        }
    };

    auto WRITE = [&](int buf) {
        #pragma unroll
        for (int i = 0; i < 4; ++i) {
            *(uint2*)&sT[buf][0][ds + i][kq * 4] =
                make_uint2(pk(st[0][i], st[1][i]), pk(st[2][i], st[3][i]));
            *(uint2*)&sT[buf][1][ds + i][kq * 4] =
                make_uint2(pk(st[4][i], st[5][i]), pk(st[6][i], st[7][i]));
        }
    };

    const int m0  = (w & 1) * 32;     // b quadrant
    const int nl0 = (w >> 1) * 32;    // local d quadrant

    f32x4 accRe[2][2] = {};
    f32x4 accIm[2][2] = {};

    auto COMPUTE = [&](int t, int buf) {
        const int k0 = t * 64;
        uint4 aRe[2][2], aIm[2][2];
        #pragma unroll
        for (int ms = 0; ms < 2; ++ms) {
            const size_t rowo = (size_t)(m0 + ms * 16 + r) * K_DIM;
            #pragma unroll
            for (int kk = 0; kk < 2; ++kk) {
                aRe[ms][kk] = *(const uint4*)&CreBf[rowo + k0 + kk * 32 + g * 8];
                aIm[ms][kk] = *(const uint4*)&CimBf[rowo + k0 + kk * 32 + g * 8];
            }
        }
        #pragma unroll
        for (int kk = 0; kk < 2; ++kk) {
            uint4 bre[2], bim[2];
            #pragma unroll
            for (int ns = 0; ns < 2; ++ns) {
                bre[ns] = *(const uint4*)&sT[buf][0][nl0 + ns * 16 + r][kk * 32 + g * 8];
                bim[ns] = *(const uint4*)&sT[buf][1][nl0 + ns * 16 + r][kk * 32 + g * 8];
            }
            #pragma unroll
            for (int ms = 0; ms < 2; ++ms)
            #pragma unroll
            for (int ns = 0; ns < 2; ++ns) {
                // out_re += cre*Bre - cim*Bim ; out_im += cre*Bim + cim*Bre
                accRe[ms][ns] = mfma16(asbf(aRe[ms][kk]), asbf(bre[ns]), accRe[ms][ns]);
                accRe[ms][ns] = mfma16(asbf(neg4(aIm[ms][kk])), asbf(bim[ns]), accRe[ms][ns]);
                if (WIM) {
                    accIm[ms][ns] = mfma16(asbf(aRe[ms][kk]), asbf(bim[ns]), accIm[ms][ns]);
                    accIm[ms][ns] = mfma16(asbf(aIm[ms][kk]), asbf(bre[ns]), accIm[ms][ns]);
                }
            }
        }
    };

    const int NT = K_DIM / 64;  // 32
    LOADS(0); WRITE(0); __syncthreads();
    for (int t = 0; t < NT; ++t) {
        if (t + 1 < NT) LOADS(t + 1);
        COMPUTE(t, t & 1);
        if (t + 1 < NT) WRITE((t + 1) & 1);
        __syncthreads();
    }

    #pragma unroll
    for (int ms = 0; ms < 2; ++ms)
    #pragma unroll
    for (int ns = 0; ns < 2; ++ns) {
        const int d = d0 + nl0 + ns * 16 + r;
        if (d < D_DIM) {
            #pragma unroll
            for (int i = 0; i < 4; ++i) {
                const int b = m0 + ms * 16 + g * 4 + i;
                if (!WIM) {
                    out[(size_t)b * D_DIM + d] = accRe[ms][ns][i];
                } else {
                    out[((size_t)b * D_DIM + d) * 2]     = accRe[ms][ns][i];
                    out[((size_t)b * D_DIM + d) * 2 + 1] = accIm[ms][ns][i];
                }
            }
        }
    }
}

extern "C" void kernel_launch(void* const* d_in, const int* in_sizes, int n_in,
                              void* d_out, int out_size, void* d_ws, size_t ws_size,
                              hipStream_t stream) {
    const float* Xre = (const float*)d_in[0];
    const float* Xim = (const float*)d_in[1];
    const float* Bre = (const float*)d_in[2];
    const float* Bim = (const float*)d_in[3];
    const float* Wre = (const float*)d_in[4];
    const float* Wim = (const float*)d_in[5];

    float*  Cre   = (float*)d_ws;                          // 512 KB
    float*  Cim   = Cre + B_DIM * K_DIM;                   // 512 KB
    __bf16* CreBf = (__bf16*)(Cim + B_DIM * K_DIM);        // 256 KB
    __bf16* CimBf = CreBf + B_DIM * K_DIM;                 // 256 KB

    (void)hipMemsetAsync(d_ws, 0, (size_t)2 * B_DIM * K_DIM * sizeof(float), stream);

    dim3 g1(32, 32);
    p1_coeffs<<<g1, 256, 0, stream>>>(Xre, Xim, Bre, Bim, Wre, Wim, Cre, Cim);

    cbf_kernel<<<(B_DIM * K_DIM + 255) / 256, 256, 0, stream>>>(Cre, Cim, CreBf, CimBf);

    const int ndt = (D_DIM + 63) / 64;  // 507
    if (out_size == 2 * B_DIM * D_DIM) {
        p2_project<true><<<ndt, 256, 0, stream>>>(Bre, Bim, CreBf, CimBf, (float*)d_out);
    } else {
        p2_project<false><<<ndt, 256, 0, stream>>>(Bre, Bim, CreBf, CimBf, (float*)d_out);
    }
}

// Round 3
// 350.567 us; speedup vs baseline: 2.8701x; 1.1027x over previous
//
#include <hip/hip_runtime.h>
#include <hip/hip_bf16.h>
#include <cstdint>
#include <cstddef>

#define B_DIM 64
#define K_DIM 2048
#define D_DIM 32400

typedef __bf16 bf16x8 __attribute__((ext_vector_type(8)));
typedef float f32x4 __attribute__((ext_vector_type(4)));

union U128 { uint4 u; bf16x8 b; };

__device__ inline bf16x8 asbf(uint4 u) { U128 x; x.u = u; return x.b; }

__device__ inline uint4 neg4(uint4 u) {
    u.x ^= 0x80008000u; u.y ^= 0x80008000u; u.z ^= 0x80008000u; u.w ^= 0x80008000u;
    return u;
}

__device__ inline f32x4 mfma16(bf16x8 a, bf16x8 b, f32x4 c) {
    return __builtin_amdgcn_mfma_f32_16x16x32_bf16(a, b, c, 0, 0, 0);
}

// guarded float4 load: element index d within row pointer p, limit dlim
__device__ inline f32x4 ld4g(const float* __restrict__ p, int d, int dlim) {
    f32x4 r;
    if (d + 4 <= dlim) {
        float4 v = *reinterpret_cast<const float4*>(p + d);
        r[0] = v.x; r[1] = v.y; r[2] = v.z; r[3] = v.w;
    } else {
        #pragma unroll
        for (int j = 0; j < 4; ++j) r[j] = (d + j < dlim) ? p[d + j] : 0.0f;
    }
    return r;
}

// pack two floats -> dword of 2 bf16 (lo = a, hi = b)
__device__ inline uint32_t pk(float a, float b) {
    union { __bf16 h[2]; uint32_t u; } x;
    x.h[0] = (__bf16)a; x.h[1] = (__bf16)b;
    return x.u;
}

// ---------------------------------------------------------------------------
// Phase 1: coeffs[b,k] = (sum_d X[b,d]*conj(bases[k,d])) * w[k], split-D atomic
// Staged LDS GEMM: tiles [64 rows][32 d] of X and bases as bf16, double-buffered.
// Grid is (x=dc, y=kt) so xcd = bid%8 = dc%8: blocks resident on one XCD share
// only 4 d-chunks of X (2 MB) -> X re-reads are L2 hits, not L3 traffic.
// ---------------------------------------------------------------------------
#define P1_STRIDE 40  // 32 d + 8 pad (80B rows: 16B aligned, spreads banks)

__global__ __launch_bounds__(256) void p1_coeffs(
    const float* __restrict__ Xre, const float* __restrict__ Xim,
    const float* __restrict__ Bre, const float* __restrict__ Bim,
    const float* __restrict__ Wre, const float* __restrict__ Wim,
    float* __restrict__ Cre, float* __restrict__ Cim)
{
    __shared__ __align__(16) __bf16 sX[2][2][64][P1_STRIDE];
    __shared__ __align__(16) __bf16 sB[2][2][64][P1_STRIDE];

    const int dc = blockIdx.x;        // 32 d-chunks of 1024  (xcd = dc%8)
    const int kt = blockIdx.y;        // 32 k-tiles of 64
    const int tid  = threadIdx.x;
    const int lane = tid & 63;
    const int w    = tid >> 6;
    const int r    = lane & 15;
    const int g    = lane >> 4;

    const int kbase  = kt * 64;
    const int dstart = dc * 1024;
    const int dend   = min(dstart + 1024, D_DIM);
    const int nsteps = (dend - dstart + 31) >> 5;

    // staging map: thread handles rows (tid>>3) and (tid>>3)+32 at d=(tid&7)*4
    const int srow = tid >> 3;          // 0..31
    const int sd   = (tid & 7) * 4;     // 0..28

    const size_t xo0 = (size_t)srow * D_DIM;
    const size_t xo1 = (size_t)(srow + 32) * D_DIM;
    const size_t bo0 = (size_t)(kbase + srow) * D_DIM;
    const size_t bo1 = (size_t)(kbase + srow + 32) * D_DIM;

    f32x4 st[8];

    auto LOADS = [&](int s) {
        const int dg = dstart + s * 32 + sd;
        st[0] = ld4g(Xre + xo0, dg, dend);
        st[1] = ld4g(Xre + xo1, dg, dend);
        st[2] = ld4g(Xim + xo0, dg, dend);
        st[3] = ld4g(Xim + xo1, dg, dend);
        st[4] = ld4g(Bre + bo0, dg, dend);
        st[5] = ld4g(Bre + bo1, dg, dend);
        st[6] = ld4g(Bim + bo0, dg, dend);
        st[7] = ld4g(Bim + bo1, dg, dend);
    };

    auto WRITE = [&](int buf) {
        *(uint2*)&sX[buf][0][srow][sd]      = make_uint2(pk(st[0][0], st[0][1]), pk(st[0][2], st[0][3]));
        *(uint2*)&sX[buf][0][srow + 32][sd] = make_uint2(pk(st[1][0], st[1][1]), pk(st[1][2], st[1][3]));
        *(uint2*)&sX[buf][1][srow][sd]      = make_uint2(pk(st[2][0], st[2][1]), pk(st[2][2], st[2][3]));
        *(uint2*)&sX[buf][1][srow + 32][sd] = make_uint2(pk(st[3][0], st[3][1]), pk(st[3][2], st[3][3]));
        *(uint2*)&sB[buf][0][srow][sd]      = make_uint2(pk(st[4][0], st[4][1]), pk(st[4][2], st[4][3]));
        *(uint2*)&sB[buf][0][srow + 32][sd] = make_uint2(pk(st[5][0], st[5][1]), pk(st[5][2], st[5][3]));
        *(uint2*)&sB[buf][1][srow][sd]      = make_uint2(pk(st[6][0], st[6][1]), pk(st[6][2], st[6][3]));
        *(uint2*)&sB[buf][1][srow + 32][sd] = make_uint2(pk(st[7][0], st[7][1]), pk(st[7][2], st[7][3]));
    };

    const int m0  = (w & 1) * 32;     // local b quadrant
    const int nl0 = (w >> 1) * 32;    // local k quadrant

    f32x4 accRe[2][2] = {};
    f32x4 accIm[2][2] = {};

    auto COMPUTE = [&](int buf) {
        uint4 xre[2], xim[2], bre[2], bim[2];
        #pragma unroll
        for (int ms = 0; ms < 2; ++ms) {
            xre[ms] = *(const uint4*)&sX[buf][0][m0 + ms * 16 + r][g * 8];
            xim[ms] = *(const uint4*)&sX[buf][1][m0 + ms * 16 + r][g * 8];
        }
        #pragma unroll
        for (int ns = 0; ns < 2; ++ns) {
            bre[ns] = *(const uint4*)&sB[buf][0][nl0 + ns * 16 + r][g * 8];
            bim[ns] = *(const uint4*)&sB[buf][1][nl0 + ns * 16 + r][g * 8];
        }
        #pragma unroll
        for (int ms = 0; ms < 2; ++ms)
        #pragma unroll
        for (int ns = 0; ns < 2; ++ns) {
            // C_re += Xre*Bre + Xim*Bim ; C_im += Xim*Bre - Xre*Bim
            accRe[ms][ns] = mfma16(asbf(xre[ms]), asbf(bre[ns]), accRe[ms][ns]);
            accRe[ms][ns] = mfma16(asbf(xim[ms]), asbf(bim[ns]), accRe[ms][ns]);
            accIm[ms][ns] = mfma16(asbf(xim[ms]), asbf(bre[ns]), accIm[ms][ns]);
            accIm[ms][ns] = mfma16(asbf(neg4(xre[ms])), asbf(bim[ns]), accIm[ms][ns]);
        }
    };

    LOADS(0); WRITE(0); __syncthreads();
    for (int s = 0; s < nsteps; ++s) {
        if (s + 1 < nsteps) LOADS(s + 1);
        COMPUTE(s & 1);
        if (s + 1 < nsteps) WRITE((s + 1) & 1);
        __syncthreads();
    }

    // epilogue: scale by w[k], atomic accumulate (C/D: col=lane&15, row=g*4+i)
    #pragma unroll
    for (int ms = 0; ms < 2; ++ms)
    #pragma unroll
    for (int ns = 0; ns < 2; ++ns) {
        const int kb = kbase + nl0 + ns * 16 + r;
        const float wre = Wre[kb], wim = Wim[kb];
        #pragma unroll
        for (int i = 0; i < 4; ++i) {
            const int b = m0 + ms * 16 + g * 4 + i;
            const float cre = accRe[ms][ns][i];
            const float cim = accIm[ms][ns][i];
            atomicAdd(&Cre[b * K_DIM + kb], cre * wre - cim * wim);
            atomicAdd(&Cim[b * K_DIM + kb], cre * wim + cim * wre);
        }
    }
}

// ---------------------------------------------------------------------------
// Phase 1.5: coeffs f32 -> bf16
// ---------------------------------------------------------------------------
__global__ __launch_bounds__(256) void cbf_kernel(
    const float* __restrict__ Cre, const float* __restrict__ Cim,
    __bf16* __restrict__ CreBf, __bf16* __restrict__ CimBf)
{
    const int i = blockIdx.x * 256 + threadIdx.x;
    if (i < B_DIM * K_DIM) {
        CreBf[i] = (__bf16)Cre[i];
        CimBf[i] = (__bf16)Cim[i];
    }
}

// ---------------------------------------------------------------------------
// Phase 2: out[b,d] += sum_{k in half} coeffs[b,k] * bases[k,d]
// K split in 2 halves (grid.y) for 4 blocks/CU occupancy; f32 atomicAdd into
// pre-zeroed out. bases tile [64 k][64 d] staged TRANSPOSED into LDS [d][k].
// ---------------------------------------------------------------------------
#define P2_STRIDE 72  // 64 k + 8 pad (144B rows, 16B aligned)

template <bool WIM>
__global__ __launch_bounds__(256) void p2_project(
    const float* __restrict__ Bre, const float* __restrict__ Bim,
    const __bf16* __restrict__ CreBf, const __bf16* __restrict__ CimBf,
    float* __restrict__ out)
{
    __shared__ __align__(16) __bf16 sT[2][2][64][P2_STRIDE];  // [buf][mat][d][k]

    const int dt = blockIdx.x;
    const int kh = blockIdx.y;        // k half: 0 -> [0,1024), 1 -> [1024,2048)
    const int d0 = dt * 64;
    const int khbase = kh * (K_DIM / 2);
    const int tid  = threadIdx.x;
    const int lane = tid & 63;
    const int w    = tid >> 6;
    const int r    = lane & 15;
    const int g    = lane >> 4;

    // staging map: thread t handles k-rows 4*(t>>4)..+3 at d = (t&15)*4
    const int kq = tid >> 4;          // 0..15
    const int ds = (tid & 15) * 4;    // 0..60

    f32x4 st[8];  // 4 k-rows x {re, im}

    auto LOADS = [&](int t) {
        const int k0 = khbase + t * 64;
        #pragma unroll
        for (int j = 0; j < 4; ++j) {
            const size_t ro = (size_t)(k0 + kq * 4 + j) * D_DIM;
            st[j]     = ld4g(Bre + ro, d0 + ds, D_DIM);
            st[4 + j] = ld4g(Bim + ro, d0 + ds, D_DIM);
        }
    };

    auto WRITE = [&](int buf) {
        #pragma unroll
        for (int i = 0; i < 4; ++i) {
            *(uint2*)&sT[buf][0][ds + i][kq * 4] =
                make_uint2(pk(st[0][i], st[1][i]), pk(st[2][i], st[3][i]));
            *(uint2*)&sT[buf][1][ds + i][kq * 4] =
                make_uint2(pk(st[4][i], st[5][i]), pk(st[6][i], st[7][i]));
        }
    };

    const int m0  = (w & 1) * 32;     // b quadrant
    const int nl0 = (w >> 1) * 32;    // local d quadrant

    f32x4 accRe[2][2] = {};
    f32x4 accIm[2][2] = {};

    auto COMPUTE = [&](int t, int buf) {
        const int k0 = khbase + t * 64;
        uint4 aRe[2][2], aIm[2][2];
        #pragma unroll
        for (int ms = 0; ms < 2; ++ms) {
            const size_t rowo = (size_t)(m0 + ms * 16 + r) * K_DIM;
            #pragma unroll
            for (int kk = 0; kk < 2; ++kk) {
                aRe[ms][kk] = *(const uint4*)&CreBf[rowo + k0 + kk * 32 + g * 8];
                aIm[ms][kk] = *(const uint4*)&CimBf[rowo + k0 + kk * 32 + g * 8];
            }
        }
        #pragma unroll
        for (int kk = 0; kk < 2; ++kk) {
            uint4 bre[2], bim[2];
            #pragma unroll
            for (int ns = 0; ns < 2; ++ns) {
                bre[ns] = *(const uint4*)&sT[buf][0][nl0 + ns * 16 + r][kk * 32 + g * 8];
                bim[ns] = *(const uint4*)&sT[buf][1][nl0 + ns * 16 + r][kk * 32 + g * 8];
            }
            #pragma unroll
            for (int ms = 0; ms < 2; ++ms)
            #pragma unroll
            for (int ns = 0; ns < 2; ++ns) {
                // out_re += cre*Bre - cim*Bim ; out_im += cre*Bim + cim*Bre
                accRe[ms][ns] = mfma16(asbf(aRe[ms][kk]), asbf(bre[ns]), accRe[ms][ns]);
                accRe[ms][ns] = mfma16(asbf(neg4(aIm[ms][kk])), asbf(bim[ns]), accRe[ms][ns]);
                if (WIM) {
                    accIm[ms][ns] = mfma16(asbf(aRe[ms][kk]), asbf(bim[ns]), accIm[ms][ns]);
                    accIm[ms][ns] = mfma16(asbf(aIm[ms][kk]), asbf(bre[ns]), accIm[ms][ns]);
                }
            }
        }
    };

    const int NT = (K_DIM / 2) / 64;  // 16
    LOADS(0); WRITE(0); __syncthreads();
    for (int t = 0; t < NT; ++t) {
        if (t + 1 < NT) LOADS(t + 1);
        COMPUTE(t, t & 1);
        if (t + 1 < NT) WRITE((t + 1) & 1);
        __syncthreads();
    }

    #pragma unroll
    for (int ms = 0; ms < 2; ++ms)
    #pragma unroll
    for (int ns = 0; ns < 2; ++ns) {
        const int d = d0 + nl0 + ns * 16 + r;
        if (d < D_DIM) {
            #pragma unroll
            for (int i = 0; i < 4; ++i) {
                const int b = m0 + ms * 16 + g * 4 + i;
                if (!WIM) {
                    atomicAdd(&out[(size_t)b * D_DIM + d], accRe[ms][ns][i]);
                } else {
                    atomicAdd(&out[((size_t)b * D_DIM + d) * 2],     accRe[ms][ns][i]);
                    atomicAdd(&out[((size_t)b * D_DIM + d) * 2 + 1], accIm[ms][ns][i]);
                }
            }
        }
    }
}

extern "C" void kernel_launch(void* const* d_in, const int* in_sizes, int n_in,
                              void* d_out, int out_size, void* d_ws, size_t ws_size,
                              hipStream_t stream) {
    const float* Xre = (const float*)d_in[0];
    const float* Xim = (const float*)d_in[1];
    const float* Bre = (const float*)d_in[2];
    const float* Bim = (const float*)d_in[3];
    const float* Wre = (const float*)d_in[4];
    const float* Wim = (const float*)d_in[5];

    float*  Cre   = (float*)d_ws;                          // 512 KB
    float*  Cim   = Cre + B_DIM * K_DIM;                   // 512 KB
    __bf16* CreBf = (__bf16*)(Cim + B_DIM * K_DIM);        // 256 KB
    __bf16* CimBf = CreBf + B_DIM * K_DIM;                 // 256 KB

    (void)hipMemsetAsync(d_ws, 0, (size_t)2 * B_DIM * K_DIM * sizeof(float), stream);
    (void)hipMemsetAsync(d_out, 0, (size_t)out_size * sizeof(float), stream);

    dim3 g1(32, 32);  // x = d-chunk (drives XCD assignment), y = k-tile
    p1_coeffs<<<g1, 256, 0, stream>>>(Xre, Xim, Bre, Bim, Wre, Wim, Cre, Cim);

    cbf_kernel<<<(B_DIM * K_DIM + 255) / 256, 256, 0, stream>>>(Cre, Cim, CreBf, CimBf);

    const int ndt = (D_DIM + 63) / 64;  // 507
    dim3 g2(ndt, 2);
    if (out_size == 2 * B_DIM * D_DIM) {
        p2_project<true><<<g2, 256, 0, stream>>>(Bre, Bim, CreBf, CimBf, (float*)d_out);
    } else {
        p2_project<false><<<g2, 256, 0, stream>>>(Bre, Bim, CreBf, CimBf, (float*)d_out);
    }
}

// Round 4
// 331.244 us; speedup vs baseline: 3.0375x; 1.0583x over previous
//
#include <hip/hip_runtime.h>
#include <hip/hip_bf16.h>
#include <cstdint>
#include <cstddef>

#define B_DIM 64
#define K_DIM 2048
#define D_DIM 32400

typedef __bf16 bf16x8 __attribute__((ext_vector_type(8)));
typedef float f32x4 __attribute__((ext_vector_type(4)));

union U128 { uint4 u; bf16x8 b; };

__device__ inline bf16x8 asbf(uint4 u) { U128 x; x.u = u; return x.b; }

__device__ inline uint4 neg4(uint4 u) {
    u.x ^= 0x80008000u; u.y ^= 0x80008000u; u.z ^= 0x80008000u; u.w ^= 0x80008000u;
    return u;
}

__device__ inline f32x4 mfma16(bf16x8 a, bf16x8 b, f32x4 c) {
    return __builtin_amdgcn_mfma_f32_16x16x32_bf16(a, b, c, 0, 0, 0);
}

// guarded float4 load: element index d within row pointer p, limit dlim
__device__ inline f32x4 ld4g(const float* __restrict__ p, int d, int dlim) {
    f32x4 r;
    if (d + 4 <= dlim) {
        float4 v = *reinterpret_cast<const float4*>(p + d);
        r[0] = v.x; r[1] = v.y; r[2] = v.z; r[3] = v.w;
    } else {
        #pragma unroll
        for (int j = 0; j < 4; ++j) r[j] = (d + j < dlim) ? p[d + j] : 0.0f;
    }
    return r;
}

// pack two floats -> dword of 2 bf16 (lo = a, hi = b)
__device__ inline uint32_t pk(float a, float b) {
    union { __bf16 h[2]; uint32_t u; } x;
    x.h[0] = (__bf16)a; x.h[1] = (__bf16)b;
    return x.u;
}

// ---------------------------------------------------------------------------
// Phase 1: coeffs[b,k] = (sum_d X[b,d]*conj(bases[k,d])) * w[k], split-D atomic
// KS=64: each bases/X row is visited in 256B-contiguous chunks (DRAM page
// locality — the 128B-visit version achieved only 1.45 TB/s). Tiles [64][64]
// bf16 x4 (Xre,Xim,Bre,Bim), double-buffered (72 KB LDS, 2 blocks/CU).
// Grid (x=dc, y=kt): xcd = dc%8 -> X re-reads are XCD-L2-local.
// ---------------------------------------------------------------------------
#define P1_STRIDE 72  // 64 d + 8 pad (144B rows; ds_read_b128 at bank floor)

__global__ __launch_bounds__(256) void p1_coeffs(
    const float* __restrict__ Xre, const float* __restrict__ Xim,
    const float* __restrict__ Bre, const float* __restrict__ Bim,
    const float* __restrict__ Wre, const float* __restrict__ Wim,
    float* __restrict__ Cre, float* __restrict__ Cim)
{
    __shared__ __align__(16) __bf16 sX[2][2][64][P1_STRIDE];
    __shared__ __align__(16) __bf16 sB[2][2][64][P1_STRIDE];

    const int dc = blockIdx.x;        // 32 d-chunks of 1024  (xcd = dc%8)
    const int kt = blockIdx.y;        // 32 k-tiles of 64
    const int tid  = threadIdx.x;
    const int lane = tid & 63;
    const int w    = tid >> 6;
    const int r    = lane & 15;
    const int g    = lane >> 4;

    const int kbase  = kt * 64;
    const int dstart = dc * 1024;
    const int dend   = min(dstart + 1024, D_DIM);
    const int nsteps = (dend - dstart + 63) >> 6;

    // staging map: thread covers row = tid>>2; lane-group c = tid&3 loads
    // float4 at d = c*4 + j*16 (j=0..3) -> each instruction j is a contiguous
    // 64B segment per row; 4 instructions cover the row's 256B window.
    const int srow = tid >> 2;          // 0..63
    const int sc   = (tid & 3) * 4;     // 0,4,8,12

    const size_t xo = (size_t)srow * D_DIM;
    const size_t bo = (size_t)(kbase + srow) * D_DIM;

    f32x4 st[16];

    auto LOADS = [&](int s) {
        const int dg = dstart + s * 64 + sc;
        #pragma unroll
        for (int j = 0; j < 4; ++j) st[j]      = ld4g(Xre + xo, dg + j * 16, dend);
        #pragma unroll
        for (int j = 0; j < 4; ++j) st[4 + j]  = ld4g(Xim + xo, dg + j * 16, dend);
        #pragma unroll
        for (int j = 0; j < 4; ++j) st[8 + j]  = ld4g(Bre + bo, dg + j * 16, dend);
        #pragma unroll
        for (int j = 0; j < 4; ++j) st[12 + j] = ld4g(Bim + bo, dg + j * 16, dend);
    };

    auto WRITE = [&](int buf) {
        #pragma unroll
        for (int j = 0; j < 4; ++j) {
            const int dp = sc + j * 16;
            *(uint2*)&sX[buf][0][srow][dp] = make_uint2(pk(st[j][0],      st[j][1]),      pk(st[j][2],      st[j][3]));
            *(uint2*)&sX[buf][1][srow][dp] = make_uint2(pk(st[4 + j][0],  st[4 + j][1]),  pk(st[4 + j][2],  st[4 + j][3]));
            *(uint2*)&sB[buf][0][srow][dp] = make_uint2(pk(st[8 + j][0],  st[8 + j][1]),  pk(st[8 + j][2],  st[8 + j][3]));
            *(uint2*)&sB[buf][1][srow][dp] = make_uint2(pk(st[12 + j][0], st[12 + j][1]), pk(st[12 + j][2], st[12 + j][3]));
        }
    };

    const int m0  = (w & 1) * 32;     // local b quadrant
    const int nl0 = (w >> 1) * 32;    // local k quadrant

    f32x4 accRe[2][2] = {};
    f32x4 accIm[2][2] = {};

    auto COMPUTE = [&](int buf) {
        #pragma unroll
        for (int kk = 0; kk < 2; ++kk) {
            const int dp = kk * 32 + g * 8;
            uint4 xre[2], xim[2], bre[2], bim[2];
            #pragma unroll
            for (int ms = 0; ms < 2; ++ms) {
                xre[ms] = *(const uint4*)&sX[buf][0][m0 + ms * 16 + r][dp];
                xim[ms] = *(const uint4*)&sX[buf][1][m0 + ms * 16 + r][dp];
            }
            #pragma unroll
            for (int ns = 0; ns < 2; ++ns) {
                bre[ns] = *(const uint4*)&sB[buf][0][nl0 + ns * 16 + r][dp];
                bim[ns] = *(const uint4*)&sB[buf][1][nl0 + ns * 16 + r][dp];
            }
            #pragma unroll
            for (int ms = 0; ms < 2; ++ms)
            #pragma unroll
            for (int ns = 0; ns < 2; ++ns) {
                // C_re += Xre*Bre + Xim*Bim ; C_im += Xim*Bre - Xre*Bim
                accRe[ms][ns] = mfma16(asbf(xre[ms]), asbf(bre[ns]), accRe[ms][ns]);
                accRe[ms][ns] = mfma16(asbf(xim[ms]), asbf(bim[ns]), accRe[ms][ns]);
                accIm[ms][ns] = mfma16(asbf(xim[ms]), asbf(bre[ns]), accIm[ms][ns]);
                accIm[ms][ns] = mfma16(asbf(neg4(xre[ms])), asbf(bim[ns]), accIm[ms][ns]);
            }
        }
    };

    LOADS(0); WRITE(0); __syncthreads();
    for (int s = 0; s < nsteps; ++s) {
        if (s + 1 < nsteps) LOADS(s + 1);
        COMPUTE(s & 1);
        if (s + 1 < nsteps) WRITE((s + 1) & 1);
        __syncthreads();
    }

    // epilogue: scale by w[k], atomic accumulate (C/D: col=lane&15, row=g*4+i)
    #pragma unroll
    for (int ms = 0; ms < 2; ++ms)
    #pragma unroll
    for (int ns = 0; ns < 2; ++ns) {
        const int kb = kbase + nl0 + ns * 16 + r;
        const float wre = Wre[kb], wim = Wim[kb];
        #pragma unroll
        for (int i = 0; i < 4; ++i) {
            const int b = m0 + ms * 16 + g * 4 + i;
            const float cre = accRe[ms][ns][i];
            const float cim = accIm[ms][ns][i];
            atomicAdd(&Cre[b * K_DIM + kb], cre * wre - cim * wim);
            atomicAdd(&Cim[b * K_DIM + kb], cre * wim + cim * wre);
        }
    }
}

// ---------------------------------------------------------------------------
// Phase 1.5: coeffs f32 -> bf16
// ---------------------------------------------------------------------------
__global__ __launch_bounds__(256) void cbf_kernel(
    const float* __restrict__ Cre, const float* __restrict__ Cim,
    __bf16* __restrict__ CreBf, __bf16* __restrict__ CimBf)
{
    const int i = blockIdx.x * 256 + threadIdx.x;
    if (i < B_DIM * K_DIM) {
        CreBf[i] = (__bf16)Cre[i];
        CimBf[i] = (__bf16)Cim[i];
    }
}

// ---------------------------------------------------------------------------
// Phase 2: out[b,d] += sum_{k in half} coeffs[b,k] * bases[k,d]
// K split in 2 halves (grid.y) for 4 blocks/CU occupancy; f32 atomicAdd into
// pre-zeroed out. bases tile [64 k][64 d] staged TRANSPOSED into LDS [d][k].
// ---------------------------------------------------------------------------
#define P2_STRIDE 72  // 64 k + 8 pad (144B rows, 16B aligned)

template <bool WIM>
__global__ __launch_bounds__(256) void p2_project(
    const float* __restrict__ Bre, const float* __restrict__ Bim,
    const __bf16* __restrict__ CreBf, const __bf16* __restrict__ CimBf,
    float* __restrict__ out)
{
    __shared__ __align__(16) __bf16 sT[2][2][64][P2_STRIDE];  // [buf][mat][d][k]

    const int dt = blockIdx.x;
    const int kh = blockIdx.y;        // k half: 0 -> [0,1024), 1 -> [1024,2048)
    const int d0 = dt * 64;
    const int khbase = kh * (K_DIM / 2);
    const int tid  = threadIdx.x;
    const int lane = tid & 63;
    const int w    = tid >> 6;
    const int r    = lane & 15;
    const int g    = lane >> 4;

    // staging map: thread t handles k-rows 4*(t>>4)..+3 at d = (t&15)*4
    const int kq = tid >> 4;          // 0..15
    const int ds = (tid & 15) * 4;    // 0..60

    f32x4 st[8];  // 4 k-rows x {re, im}

    auto LOADS = [&](int t) {
        const int k0 = khbase + t * 64;
        #pragma unroll
        for (int j = 0; j < 4; ++j) {
            const size_t ro = (size_t)(k0 + kq * 4 + j) * D_DIM;
            st[j]     = ld4g(Bre + ro, d0 + ds, D_DIM);
            st[4 + j] = ld4g(Bim + ro, d0 + ds, D_DIM);
        }
    };

    auto WRITE = [&](int buf) {
        #pragma unroll
        for (int i = 0; i < 4; ++i) {
            *(uint2*)&sT[buf][0][ds + i][kq * 4] =
                make_uint2(pk(st[0][i], st[1][i]), pk(st[2][i], st[3][i]));
            *(uint2*)&sT[buf][1][ds + i][kq * 4] =
                make_uint2(pk(st[4][i], st[5][i]), pk(st[6][i], st[7][i]));
        }
    };

    const int m0  = (w & 1) * 32;     // b quadrant
    const int nl0 = (w >> 1) * 32;    // local d quadrant

    f32x4 accRe[2][2] = {};
    f32x4 accIm[2][2] = {};

    auto COMPUTE = [&](int t, int buf) {
        const int k0 = khbase + t * 64;
        uint4 aRe[2][2], aIm[2][2];
        #pragma unroll
        for (int ms = 0; ms < 2; ++ms) {
            const size_t rowo = (size_t)(m0 + ms * 16 + r) * K_DIM;
            #pragma unroll
            for (int kk = 0; kk < 2; ++kk) {
                aRe[ms][kk] = *(const uint4*)&CreBf[rowo + k0 + kk * 32 + g * 8];
                aIm[ms][kk] = *(const uint4*)&CimBf[rowo + k0 + kk * 32 + g * 8];
            }
        }
        #pragma unroll
        for (int kk = 0; kk < 2; ++kk) {
            uint4 bre[2], bim[2];
            #pragma unroll
            for (int ns = 0; ns < 2; ++ns) {
                bre[ns] = *(const uint4*)&sT[buf][0][nl0 + ns * 16 + r][kk * 32 + g * 8];
                bim[ns] = *(const uint4*)&sT[buf][1][nl0 + ns * 16 + r][kk * 32 + g * 8];
            }
            #pragma unroll
            for (int ms = 0; ms < 2; ++ms)
            #pragma unroll
            for (int ns = 0; ns < 2; ++ns) {
                // out_re += cre*Bre - cim*Bim ; out_im += cre*Bim + cim*Bre
                accRe[ms][ns] = mfma16(asbf(aRe[ms][kk]), asbf(bre[ns]), accRe[ms][ns]);
                accRe[ms][ns] = mfma16(asbf(neg4(aIm[ms][kk])), asbf(bim[ns]), accRe[ms][ns]);
                if (WIM) {
                    accIm[ms][ns] = mfma16(asbf(aRe[ms][kk]), asbf(bim[ns]), accIm[ms][ns]);
                    accIm[ms][ns] = mfma16(asbf(aIm[ms][kk]), asbf(bre[ns]), accIm[ms][ns]);
                }
            }
        }
    };

    const int NT = (K_DIM / 2) / 64;  // 16
    LOADS(0); WRITE(0); __syncthreads();
    for (int t = 0; t < NT; ++t) {
        if (t + 1 < NT) LOADS(t + 1);
        COMPUTE(t, t & 1);
        if (t + 1 < NT) WRITE((t + 1) & 1);
        __syncthreads();
    }

    #pragma unroll
    for (int ms = 0; ms < 2; ++ms)
    #pragma unroll
    for (int ns = 0; ns < 2; ++ns) {
        const int d = d0 + nl0 + ns * 16 + r;
        if (d < D_DIM) {
            #pragma unroll
            for (int i = 0; i < 4; ++i) {
                const int b = m0 + ms * 16 + g * 4 + i;
                if (!WIM) {
                    atomicAdd(&out[(size_t)b * D_DIM + d], accRe[ms][ns][i]);
                } else {
                    atomicAdd(&out[((size_t)b * D_DIM + d) * 2],     accRe[ms][ns][i]);
                    atomicAdd(&out[((size_t)b * D_DIM + d) * 2 + 1], accIm[ms][ns][i]);
                }
            }
        }
    }
}

extern "C" void kernel_launch(void* const* d_in, const int* in_sizes, int n_in,
                              void* d_out, int out_size, void* d_ws, size_t ws_size,
                              hipStream_t stream) {
    const float* Xre = (const float*)d_in[0];
    const float* Xim = (const float*)d_in[1];
    const float* Bre = (const float*)d_in[2];
    const float* Bim = (const float*)d_in[3];
    const float* Wre = (const float*)d_in[4];
    const float* Wim = (const float*)d_in[5];

    float*  Cre   = (float*)d_ws;                          // 512 KB
    float*  Cim   = Cre + B_DIM * K_DIM;                   // 512 KB
    __bf16* CreBf = (__bf16*)(Cim + B_DIM * K_DIM);        // 256 KB
    __bf16* CimBf = CreBf + B_DIM * K_DIM;                 // 256 KB

    (void)hipMemsetAsync(d_ws, 0, (size_t)2 * B_DIM * K_DIM * sizeof(float), stream);
    (void)hipMemsetAsync(d_out, 0, (size_t)out_size * sizeof(float), stream);

    dim3 g1(32, 32);  // x = d-chunk (drives XCD assignment), y = k-tile
    p1_coeffs<<<g1, 256, 0, stream>>>(Xre, Xim, Bre, Bim, Wre, Wim, Cre, Cim);

    cbf_kernel<<<(B_DIM * K_DIM + 255) / 256, 256, 0, stream>>>(Cre, Cim, CreBf, CimBf);

    const int ndt = (D_DIM + 63) / 64;  // 507
    dim3 g2(ndt, 2);
    if (out_size == 2 * B_DIM * D_DIM) {
        p2_project<true><<<g2, 256, 0, stream>>>(Bre, Bim, CreBf, CimBf, (float*)d_out);
    } else {
        p2_project<false><<<g2, 256, 0, stream>>>(Bre, Bim, CreBf, CimBf, (float*)d_out);
    }
}

// Round 5
// 325.557 us; speedup vs baseline: 3.0906x; 1.0175x over previous
//
#include <hip/hip_runtime.h>
#include <hip/hip_bf16.h>
#include <cstdint>
#include <cstddef>

#define B_DIM 64
#define K_DIM 2048
#define D_DIM 32400

typedef __bf16 bf16x8 __attribute__((ext_vector_type(8)));
typedef float f32x4 __attribute__((ext_vector_type(4)));

union U128 { uint4 u; bf16x8 b; };

__device__ inline bf16x8 asbf(uint4 u) { U128 x; x.u = u; return x.b; }

__device__ inline uint4 neg4(uint4 u) {
    u.x ^= 0x80008000u; u.y ^= 0x80008000u; u.z ^= 0x80008000u; u.w ^= 0x80008000u;
    return u;
}

__device__ inline f32x4 mfma16(bf16x8 a, bf16x8 b, f32x4 c) {
    return __builtin_amdgcn_mfma_f32_16x16x32_bf16(a, b, c, 0, 0, 0);
}

// guarded float4 load: element index d within row pointer p, limit dlim
__device__ inline f32x4 ld4g(const float* __restrict__ p, int d, int dlim) {
    f32x4 r;
    if (d + 4 <= dlim) {
        float4 v = *reinterpret_cast<const float4*>(p + d);
        r[0] = v.x; r[1] = v.y; r[2] = v.z; r[3] = v.w;
    } else {
        #pragma unroll
        for (int j = 0; j < 4; ++j) r[j] = (d + j < dlim) ? p[d + j] : 0.0f;
    }
    return r;
}

// pack two floats -> dword of 2 bf16 (lo = a, hi = b)
__device__ inline uint32_t pk(float a, float b) {
    union { __bf16 h[2]; uint32_t u; } x;
    x.h[0] = (__bf16)a; x.h[1] = (__bf16)b;
    return x.u;
}

// ---------------------------------------------------------------------------
// Phase 1: coeffs[b,k] = (sum_d X[b,d]*conj(bases[k,d])) * w[k], split-D atomic.
// KS=64. Staging: 16 lanes x float4 = 256B contiguous per row per instruction
// (the per-instruction segment size is the BW lever: 64B segs -> 1.5 TB/s,
// p2's 256B segs -> 4.9 TB/s). Grid x=kt so xcd=kt%8: each XCD's bases
// stream concentrates on ~256 contiguous rows; X re-reads hit L3.
// Single-buffer LDS (36.9 KB -> 4 blocks/CU) with register prefetch.
// ---------------------------------------------------------------------------
#define P1_STRIDE 72  // 64 d + 8 pad (144B rows; ds_read_b128 2-way max)

__global__ __launch_bounds__(256) void p1_coeffs(
    const float* __restrict__ Xre, const float* __restrict__ Xim,
    const float* __restrict__ Bre, const float* __restrict__ Bim,
    const float* __restrict__ Wre, const float* __restrict__ Wim,
    float* __restrict__ Cre, float* __restrict__ Cim)
{
    __shared__ __align__(16) __bf16 sX[2][64][P1_STRIDE];  // [re/im][row][d]
    __shared__ __align__(16) __bf16 sB[2][64][P1_STRIDE];

    const int kt = blockIdx.x;        // 32 k-tiles of 64  (xcd = kt%8)
    const int dc = blockIdx.y;        // 32 d-chunks of 1024
    const int tid  = threadIdx.x;
    const int lane = tid & 63;
    const int w    = tid >> 6;
    const int r    = lane & 15;
    const int g    = lane >> 4;

    const int kbase  = kt * 64;
    const int dstart = dc * 1024;
    const int dend   = min(dstart + 1024, D_DIM);
    const int nsteps = (dend - dstart + 63) >> 6;

    // staging map: 16-lane groups, 256B contiguous per row per instruction
    const int srow = tid >> 4;          // 0..15 (+16 per j)
    const int sd   = (tid & 15) * 4;    // 0..60

    f32x4 st[16];

    auto LOADS = [&](int s) {
        const int dg = dstart + s * 64 + sd;
        #pragma unroll
        for (int j = 0; j < 4; ++j) {
            const int row = j * 16 + srow;
            st[j]      = ld4g(Xre + (size_t)row * D_DIM, dg, dend);
            st[4 + j]  = ld4g(Xim + (size_t)row * D_DIM, dg, dend);
            st[8 + j]  = ld4g(Bre + (size_t)(kbase + row) * D_DIM, dg, dend);
            st[12 + j] = ld4g(Bim + (size_t)(kbase + row) * D_DIM, dg, dend);
        }
    };

    auto WRITE = [&]() {
        #pragma unroll
        for (int j = 0; j < 4; ++j) {
            const int row = j * 16 + srow;
            *(uint2*)&sX[0][row][sd] = make_uint2(pk(st[j][0],      st[j][1]),      pk(st[j][2],      st[j][3]));
            *(uint2*)&sX[1][row][sd] = make_uint2(pk(st[4 + j][0],  st[4 + j][1]),  pk(st[4 + j][2],  st[4 + j][3]));
            *(uint2*)&sB[0][row][sd] = make_uint2(pk(st[8 + j][0],  st[8 + j][1]),  pk(st[8 + j][2],  st[8 + j][3]));
            *(uint2*)&sB[1][row][sd] = make_uint2(pk(st[12 + j][0], st[12 + j][1]), pk(st[12 + j][2], st[12 + j][3]));
        }
    };

    const int m0  = (w & 1) * 32;     // local b quadrant
    const int nl0 = (w >> 1) * 32;    // local k quadrant

    f32x4 accRe[2][2] = {};
    f32x4 accIm[2][2] = {};

    auto COMPUTE = [&]() {
        #pragma unroll
        for (int kk = 0; kk < 2; ++kk) {
            const int dp = kk * 32 + g * 8;
            uint4 xre[2], xim[2], bre[2], bim[2];
            #pragma unroll
            for (int ms = 0; ms < 2; ++ms) {
                xre[ms] = *(const uint4*)&sX[0][m0 + ms * 16 + r][dp];
                xim[ms] = *(const uint4*)&sX[1][m0 + ms * 16 + r][dp];
            }
            #pragma unroll
            for (int ns = 0; ns < 2; ++ns) {
                bre[ns] = *(const uint4*)&sB[0][nl0 + ns * 16 + r][dp];
                bim[ns] = *(const uint4*)&sB[1][nl0 + ns * 16 + r][dp];
            }
            #pragma unroll
            for (int ms = 0; ms < 2; ++ms)
            #pragma unroll
            for (int ns = 0; ns < 2; ++ns) {
                // C_re += Xre*Bre + Xim*Bim ; C_im += Xim*Bre - Xre*Bim
                accRe[ms][ns] = mfma16(asbf(xre[ms]), asbf(bre[ns]), accRe[ms][ns]);
                accRe[ms][ns] = mfma16(asbf(xim[ms]), asbf(bim[ns]), accRe[ms][ns]);
                accIm[ms][ns] = mfma16(asbf(xim[ms]), asbf(bre[ns]), accIm[ms][ns]);
                accIm[ms][ns] = mfma16(asbf(neg4(xre[ms])), asbf(bim[ns]), accIm[ms][ns]);
            }
        }
    };

    LOADS(0); WRITE(); __syncthreads();
    for (int s = 0; s < nsteps; ++s) {
        if (s + 1 < nsteps) LOADS(s + 1);
        COMPUTE();
        if (s + 1 < nsteps) {
            __syncthreads();   // all reads of the buffer done
            WRITE();           // overwrite with s+1 tile
            __syncthreads();   // writes visible
        }
    }

    // epilogue: scale by w[k], atomic accumulate (C/D: col=lane&15, row=g*4+i)
    #pragma unroll
    for (int ms = 0; ms < 2; ++ms)
    #pragma unroll
    for (int ns = 0; ns < 2; ++ns) {
        const int kb = kbase + nl0 + ns * 16 + r;
        const float wre = Wre[kb], wim = Wim[kb];
        #pragma unroll
        for (int i = 0; i < 4; ++i) {
            const int b = m0 + ms * 16 + g * 4 + i;
            const float cre = accRe[ms][ns][i];
            const float cim = accIm[ms][ns][i];
            atomicAdd(&Cre[b * K_DIM + kb], cre * wre - cim * wim);
            atomicAdd(&Cim[b * K_DIM + kb], cre * wim + cim * wre);
        }
    }
}

// ---------------------------------------------------------------------------
// Phase 1.5: coeffs f32 -> bf16
// ---------------------------------------------------------------------------
__global__ __launch_bounds__(256) void cbf_kernel(
    const float* __restrict__ Cre, const float* __restrict__ Cim,
    __bf16* __restrict__ CreBf, __bf16* __restrict__ CimBf)
{
    const int i = blockIdx.x * 256 + threadIdx.x;
    if (i < B_DIM * K_DIM) {
        CreBf[i] = (__bf16)Cre[i];
        CimBf[i] = (__bf16)Cim[i];
    }
}

// ---------------------------------------------------------------------------
// Phase 2: out[b,d] += sum_{k in half} coeffs[b,k] * bases[k,d]
// K split in 2 halves (grid.y) for 4 blocks/CU occupancy; f32 atomicAdd into
// pre-zeroed out. bases tile [64 k][64 d] staged TRANSPOSED into LDS [d][k].
// ---------------------------------------------------------------------------
#define P2_STRIDE 72  // 64 k + 8 pad (144B rows, 16B aligned)

template <bool WIM>
__global__ __launch_bounds__(256) void p2_project(
    const float* __restrict__ Bre, const float* __restrict__ Bim,
    const __bf16* __restrict__ CreBf, const __bf16* __restrict__ CimBf,
    float* __restrict__ out)
{
    __shared__ __align__(16) __bf16 sT[2][2][64][P2_STRIDE];  // [buf][mat][d][k]

    const int dt = blockIdx.x;
    const int kh = blockIdx.y;        // k half: 0 -> [0,1024), 1 -> [1024,2048)
    const int d0 = dt * 64;
    const int khbase = kh * (K_DIM / 2);
    const int tid  = threadIdx.x;
    const int lane = tid & 63;
    const int w    = tid >> 6;
    const int r    = lane & 15;
    const int g    = lane >> 4;

    // staging map: thread t handles k-rows 4*(t>>4)..+3 at d = (t&15)*4
    const int kq = tid >> 4;          // 0..15
    const int ds = (tid & 15) * 4;    // 0..60

    f32x4 st[8];  // 4 k-rows x {re, im}

    auto LOADS = [&](int t) {
        const int k0 = khbase + t * 64;
        #pragma unroll
        for (int j = 0; j < 4; ++j) {
            const size_t ro = (size_t)(k0 + kq * 4 + j) * D_DIM;
            st[j]     = ld4g(Bre + ro, d0 + ds, D_DIM);
            st[4 + j] = ld4g(Bim + ro, d0 + ds, D_DIM);
        }
    };

    auto WRITE = [&](int buf) {
        #pragma unroll
        for (int i = 0; i < 4; ++i) {
            *(uint2*)&sT[buf][0][ds + i][kq * 4] =
                make_uint2(pk(st[0][i], st[1][i]), pk(st[2][i], st[3][i]));
            *(uint2*)&sT[buf][1][ds + i][kq * 4] =
                make_uint2(pk(st[4][i], st[5][i]), pk(st[6][i], st[7][i]));
        }
    };

    const int m0  = (w & 1) * 32;     // b quadrant
    const int nl0 = (w >> 1) * 32;    // local d quadrant

    f32x4 accRe[2][2] = {};
    f32x4 accIm[2][2] = {};

    auto COMPUTE = [&](int t, int buf) {
        const int k0 = khbase + t * 64;
        uint4 aRe[2][2], aIm[2][2];
        #pragma unroll
        for (int ms = 0; ms < 2; ++ms) {
            const size_t rowo = (size_t)(m0 + ms * 16 + r) * K_DIM;
            #pragma unroll
            for (int kk = 0; kk < 2; ++kk) {
                aRe[ms][kk] = *(const uint4*)&CreBf[rowo + k0 + kk * 32 + g * 8];
                aIm[ms][kk] = *(const uint4*)&CimBf[rowo + k0 + kk * 32 + g * 8];
            }
        }
        #pragma unroll
        for (int kk = 0; kk < 2; ++kk) {
            uint4 bre[2], bim[2];
            #pragma unroll
            for (int ns = 0; ns < 2; ++ns) {
                bre[ns] = *(const uint4*)&sT[buf][0][nl0 + ns * 16 + r][kk * 32 + g * 8];
                bim[ns] = *(const uint4*)&sT[buf][1][nl0 + ns * 16 + r][kk * 32 + g * 8];
            }
            #pragma unroll
            for (int ms = 0; ms < 2; ++ms)
            #pragma unroll
            for (int ns = 0; ns < 2; ++ns) {
                // out_re += cre*Bre - cim*Bim ; out_im += cre*Bim + cim*Bre
                accRe[ms][ns] = mfma16(asbf(aRe[ms][kk]), asbf(bre[ns]), accRe[ms][ns]);
                accRe[ms][ns] = mfma16(asbf(neg4(aIm[ms][kk])), asbf(bim[ns]), accRe[ms][ns]);
                if (WIM) {
                    accIm[ms][ns] = mfma16(asbf(aRe[ms][kk]), asbf(bim[ns]), accIm[ms][ns]);
                    accIm[ms][ns] = mfma16(asbf(aIm[ms][kk]), asbf(bre[ns]), accIm[ms][ns]);
                }
            }
        }
    };

    const int NT = (K_DIM / 2) / 64;  // 16
    LOADS(0); WRITE(0); __syncthreads();
    for (int t = 0; t < NT; ++t) {
        if (t + 1 < NT) LOADS(t + 1);
        COMPUTE(t, t & 1);
        if (t + 1 < NT) WRITE((t + 1) & 1);
        __syncthreads();
    }

    #pragma unroll
    for (int ms = 0; ms < 2; ++ms)
    #pragma unroll
    for (int ns = 0; ns < 2; ++ns) {
        const int d = d0 + nl0 + ns * 16 + r;
        if (d < D_DIM) {
            #pragma unroll
            for (int i = 0; i < 4; ++i) {
                const int b = m0 + ms * 16 + g * 4 + i;
                if (!WIM) {
                    atomicAdd(&out[(size_t)b * D_DIM + d], accRe[ms][ns][i]);
                } else {
                    atomicAdd(&out[((size_t)b * D_DIM + d) * 2],     accRe[ms][ns][i]);
                    atomicAdd(&out[((size_t)b * D_DIM + d) * 2 + 1], accIm[ms][ns][i]);
                }
            }
        }
    }
}

extern "C" void kernel_launch(void* const* d_in, const int* in_sizes, int n_in,
                              void* d_out, int out_size, void* d_ws, size_t ws_size,
                              hipStream_t stream) {
    const float* Xre = (const float*)d_in[0];
    const float* Xim = (const float*)d_in[1];
    const float* Bre = (const float*)d_in[2];
    const float* Bim = (const float*)d_in[3];
    const float* Wre = (const float*)d_in[4];
    const float* Wim = (const float*)d_in[5];

    float*  Cre   = (float*)d_ws;                          // 512 KB
    float*  Cim   = Cre + B_DIM * K_DIM;                   // 512 KB
    __bf16* CreBf = (__bf16*)(Cim + B_DIM * K_DIM);        // 256 KB
    __bf16* CimBf = CreBf + B_DIM * K_DIM;                 // 256 KB

    (void)hipMemsetAsync(d_ws, 0, (size_t)2 * B_DIM * K_DIM * sizeof(float), stream);
    (void)hipMemsetAsync(d_out, 0, (size_t)out_size * sizeof(float), stream);

    dim3 g1(32, 32);  // x = k-tile (drives XCD assignment), y = d-chunk
    p1_coeffs<<<g1, 256, 0, stream>>>(Xre, Xim, Bre, Bim, Wre, Wim, Cre, Cim);

    cbf_kernel<<<(B_DIM * K_DIM + 255) / 256, 256, 0, stream>>>(Cre, Cim, CreBf, CimBf);

    const int ndt = (D_DIM + 63) / 64;  // 507
    dim3 g2(ndt, 2);
    if (out_size == 2 * B_DIM * D_DIM) {
        p2_project<true><<<g2, 256, 0, stream>>>(Bre, Bim, CreBf, CimBf, (float*)d_out);
    } else {
        p2_project<false><<<g2, 256, 0, stream>>>(Bre, Bim, CreBf, CimBf, (float*)d_out);
    }
}

// Round 6
// 303.789 us; speedup vs baseline: 3.3120x; 1.0717x over previous
//
#include <hip/hip_runtime.h>
#include <hip/hip_bf16.h>
#include <cstdint>
#include <cstddef>

#define B_DIM 64
#define K_DIM 2048
#define D_DIM 32400
#define KTILE 128

typedef __bf16 bf16x8 __attribute__((ext_vector_type(8)));
typedef float f32x4 __attribute__((ext_vector_type(4)));

union U128 { uint4 u; bf16x8 b; };

__device__ inline bf16x8 asbf(uint4 u) { U128 x; x.u = u; return x.b; }

__device__ inline uint4 neg4(uint4 u) {
    u.x ^= 0x80008000u; u.y ^= 0x80008000u; u.z ^= 0x80008000u; u.w ^= 0x80008000u;
    return u;
}

__device__ inline f32x4 mfma16(bf16x8 a, bf16x8 b, f32x4 c) {
    return __builtin_amdgcn_mfma_f32_16x16x32_bf16(a, b, c, 0, 0, 0);
}

// guarded float4 load: element index d within row pointer p, limit dlim
__device__ inline f32x4 ld4g(const float* __restrict__ p, int d, int dlim) {
    f32x4 r;
    if (d + 4 <= dlim) {
        float4 v = *reinterpret_cast<const float4*>(p + d);
        r[0] = v.x; r[1] = v.y; r[2] = v.z; r[3] = v.w;
    } else {
        #pragma unroll
        for (int j = 0; j < 4; ++j) r[j] = (d + j < dlim) ? p[d + j] : 0.0f;
    }
    return r;
}

// guarded 8x bf16 (16B) load
__device__ inline uint4 ld8bf(const __bf16* __restrict__ p, int d, int dlim) {
    if (d + 8 <= dlim) return *reinterpret_cast<const uint4*>(p + d);
    union { uint4 u; __bf16 h[8]; } x;
    #pragma unroll
    for (int j = 0; j < 8; ++j) x.h[j] = (d + j < dlim) ? p[d + j] : (__bf16)0.0f;
    return x.u;
}

// pack two floats -> dword of 2 bf16 (lo = a, hi = b)
__device__ inline uint32_t pk(float a, float b) {
    union { __bf16 h[2]; uint32_t u; } x;
    x.h[0] = (__bf16)a; x.h[1] = (__bf16)b;
    return x.u;
}

// ---------------------------------------------------------------------------
// Phase 0: X f32 -> bf16 (done once; X is re-read by every k-tile-group, so
// halving its footprint cuts p1's redundant cache-hit traffic in half).
// ---------------------------------------------------------------------------
__global__ __launch_bounds__(256) void xbf_kernel(
    const float* __restrict__ Xre, const float* __restrict__ Xim,
    __bf16* __restrict__ XreB, __bf16* __restrict__ XimB)
{
    const int i = (blockIdx.x * 256 + threadIdx.x) * 4;
    if (i < B_DIM * D_DIM) {
        float4 a = *reinterpret_cast<const float4*>(Xre + i);
        float4 b = *reinterpret_cast<const float4*>(Xim + i);
        *(uint2*)(XreB + i) = make_uint2(pk(a.x, a.y), pk(a.z, a.w));
        *(uint2*)(XimB + i) = make_uint2(pk(b.x, b.y), pk(b.z, b.w));
    }
}

// ---------------------------------------------------------------------------
// Phase 1: coeffs[b,k] = (sum_d X[b,d]*conj(bases[k,d])) * w[k], split-D atomic.
// k-tile 128 (16 groups): X re-read 16x instead of 32x. KS=64; bases staged
// with 256B-contiguous per-row segments; X staged from bf16 (or f32 fallback
// when ws is too small). Single-buffer LDS 55KB -> 2 blocks/CU.
// Grid x=ktg so xcd=ktg%8: per-XCD bases stream is 256 contiguous rows.
// ---------------------------------------------------------------------------
#define P1_STRIDE 72  // 64 d + 8 pad (144B rows; 16B-aligned subtiles)

template <bool XBF>
__global__ __launch_bounds__(256, 2) void p1_coeffs(
    const float* __restrict__ XreF, const float* __restrict__ XimF,
    const __bf16* __restrict__ XreB, const __bf16* __restrict__ XimB,
    const float* __restrict__ Bre, const float* __restrict__ Bim,
    const float* __restrict__ Wre, const float* __restrict__ Wim,
    float* __restrict__ Cre, float* __restrict__ Cim)
{
    __shared__ __align__(16) __bf16 sX[2][64][P1_STRIDE];     // [re/im][b][d]
    __shared__ __align__(16) __bf16 sB[2][KTILE][P1_STRIDE];  // [re/im][k][d]

    const int ktg = blockIdx.x;       // 16 k-groups of 128  (xcd = ktg%8)
    const int dc  = blockIdx.y;       // 32 d-chunks of 1024
    const int tid  = threadIdx.x;
    const int lane = tid & 63;
    const int w    = tid >> 6;
    const int r    = lane & 15;
    const int g    = lane >> 4;

    const int kbase  = ktg * KTILE;
    const int dstart = dc * 1024;
    const int dend   = min(dstart + 1024, D_DIM);
    const int nsteps = (dend - dstart + 63) >> 6;

    // bases staging: 16-lane groups, 256B contiguous per row per instruction
    const int srow = tid >> 4;          // 0..15 (+16 per j)
    const int sd   = (tid & 15) * 4;    // f32 elems 0..60
    // X bf16 staging: 8-lane groups, 128B contiguous per row per instruction
    const int rowx = tid >> 3;          // 0..31 (+32 per j)
    const int colx = (tid & 7) * 8;     // bf16 elems 0..56

    f32x4 bst[16];
    uint4 xst[4];
    f32x4 xstf[8];

    auto LOADS = [&](int s) {
        const int dg = dstart + s * 64 + sd;
        #pragma unroll
        for (int j = 0; j < 8; ++j) {
            const int row = j * 16 + srow;
            bst[j]     = ld4g(Bre + (size_t)(kbase + row) * D_DIM, dg, dend);
            bst[8 + j] = ld4g(Bim + (size_t)(kbase + row) * D_DIM, dg, dend);
        }
        if (XBF) {
            const int dgx = dstart + s * 64 + colx;
            xst[0] = ld8bf(XreB + (size_t)rowx * D_DIM,        dgx, dend);
            xst[1] = ld8bf(XreB + (size_t)(rowx + 32) * D_DIM, dgx, dend);
            xst[2] = ld8bf(XimB + (size_t)rowx * D_DIM,        dgx, dend);
            xst[3] = ld8bf(XimB + (size_t)(rowx + 32) * D_DIM, dgx, dend);
        } else {
            #pragma unroll
            for (int j = 0; j < 4; ++j) {
                const int row = j * 16 + srow;
                xstf[j]     = ld4g(XreF + (size_t)row * D_DIM, dg, dend);
                xstf[4 + j] = ld4g(XimF + (size_t)row * D_DIM, dg, dend);
            }
        }
    };

    auto WRITE = [&]() {
        #pragma unroll
        for (int j = 0; j < 8; ++j) {
            const int row = j * 16 + srow;
            *(uint2*)&sB[0][row][sd] = make_uint2(pk(bst[j][0],     bst[j][1]),     pk(bst[j][2],     bst[j][3]));
            *(uint2*)&sB[1][row][sd] = make_uint2(pk(bst[8 + j][0], bst[8 + j][1]), pk(bst[8 + j][2], bst[8 + j][3]));
        }
        if (XBF) {
            *(uint4*)&sX[0][rowx][colx]      = xst[0];
            *(uint4*)&sX[0][rowx + 32][colx] = xst[1];
            *(uint4*)&sX[1][rowx][colx]      = xst[2];
            *(uint4*)&sX[1][rowx + 32][colx] = xst[3];
        } else {
            #pragma unroll
            for (int j = 0; j < 4; ++j) {
                const int row = j * 16 + srow;
                *(uint2*)&sX[0][row][sd] = make_uint2(pk(xstf[j][0],     xstf[j][1]),     pk(xstf[j][2],     xstf[j][3]));
                *(uint2*)&sX[1][row][sd] = make_uint2(pk(xstf[4 + j][0], xstf[4 + j][1]), pk(xstf[4 + j][2], xstf[4 + j][3]));
            }
        }
    };

    const int m0  = (w & 1) * 32;     // local b quadrant (32 rows)
    const int nl0 = (w >> 1) * 64;    // local k span (64 cols)

    f32x4 accRe[2][4] = {};
    f32x4 accIm[2][4] = {};

    auto COMPUTE = [&]() {
        #pragma unroll
        for (int kk = 0; kk < 2; ++kk) {
            const int dp = kk * 32 + g * 8;
            uint4 xre[2], xim[2], bre[4], bim[4];
            #pragma unroll
            for (int ms = 0; ms < 2; ++ms) {
                xre[ms] = *(const uint4*)&sX[0][m0 + ms * 16 + r][dp];
                xim[ms] = *(const uint4*)&sX[1][m0 + ms * 16 + r][dp];
            }
            #pragma unroll
            for (int ns = 0; ns < 4; ++ns) {
                bre[ns] = *(const uint4*)&sB[0][nl0 + ns * 16 + r][dp];
                bim[ns] = *(const uint4*)&sB[1][nl0 + ns * 16 + r][dp];
            }
            #pragma unroll
            for (int ms = 0; ms < 2; ++ms)
            #pragma unroll
            for (int ns = 0; ns < 4; ++ns) {
                // C_re += Xre*Bre + Xim*Bim ; C_im += Xim*Bre - Xre*Bim
                accRe[ms][ns] = mfma16(asbf(xre[ms]), asbf(bre[ns]), accRe[ms][ns]);
                accRe[ms][ns] = mfma16(asbf(xim[ms]), asbf(bim[ns]), accRe[ms][ns]);
                accIm[ms][ns] = mfma16(asbf(xim[ms]), asbf(bre[ns]), accIm[ms][ns]);
                accIm[ms][ns] = mfma16(asbf(neg4(xre[ms])), asbf(bim[ns]), accIm[ms][ns]);
            }
        }
    };

    LOADS(0); WRITE(); __syncthreads();
    for (int s = 0; s < nsteps; ++s) {
        if (s + 1 < nsteps) LOADS(s + 1);
        COMPUTE();
        if (s + 1 < nsteps) {
            __syncthreads();   // all reads of the buffer done
            WRITE();           // overwrite with s+1 tile
            __syncthreads();   // writes visible
        }
    }

    // epilogue: scale by w[k], atomic accumulate (C/D: col=lane&15, row=g*4+i)
    #pragma unroll
    for (int ms = 0; ms < 2; ++ms)
    #pragma unroll
    for (int ns = 0; ns < 4; ++ns) {
        const int kb = kbase + nl0 + ns * 16 + r;
        const float wre = Wre[kb], wim = Wim[kb];
        #pragma unroll
        for (int i = 0; i < 4; ++i) {
            const int b = m0 + ms * 16 + g * 4 + i;
            const float cre = accRe[ms][ns][i];
            const float cim = accIm[ms][ns][i];
            atomicAdd(&Cre[b * K_DIM + kb], cre * wre - cim * wim);
            atomicAdd(&Cim[b * K_DIM + kb], cre * wim + cim * wre);
        }
    }
}

// ---------------------------------------------------------------------------
// Phase 1.5: coeffs f32 -> bf16
// ---------------------------------------------------------------------------
__global__ __launch_bounds__(256) void cbf_kernel(
    const float* __restrict__ Cre, const float* __restrict__ Cim,
    __bf16* __restrict__ CreBf, __bf16* __restrict__ CimBf)
{
    const int i = blockIdx.x * 256 + threadIdx.x;
    if (i < B_DIM * K_DIM) {
        CreBf[i] = (__bf16)Cre[i];
        CimBf[i] = (__bf16)Cim[i];
    }
}

// ---------------------------------------------------------------------------
// Phase 2: out[b,d] += sum_{k in half} coeffs[b,k] * bases[k,d]
// K split in 2 halves (grid.y) for 4 blocks/CU occupancy; f32 atomicAdd into
// pre-zeroed out. bases tile [64 k][64 d] staged TRANSPOSED into LDS [d][k].
// ---------------------------------------------------------------------------
#define P2_STRIDE 72  // 64 k + 8 pad (144B rows, 16B aligned)

template <bool WIM>
__global__ __launch_bounds__(256) void p2_project(
    const float* __restrict__ Bre, const float* __restrict__ Bim,
    const __bf16* __restrict__ CreBf, const __bf16* __restrict__ CimBf,
    float* __restrict__ out)
{
    __shared__ __align__(16) __bf16 sT[2][2][64][P2_STRIDE];  // [buf][mat][d][k]

    const int dt = blockIdx.x;
    const int kh = blockIdx.y;        // k half: 0 -> [0,1024), 1 -> [1024,2048)
    const int d0 = dt * 64;
    const int khbase = kh * (K_DIM / 2);
    const int tid  = threadIdx.x;
    const int lane = tid & 63;
    const int w    = tid >> 6;
    const int r    = lane & 15;
    const int g    = lane >> 4;

    // staging map: thread t handles k-rows 4*(t>>4)..+3 at d = (t&15)*4
    const int kq = tid >> 4;          // 0..15
    const int ds = (tid & 15) * 4;    // 0..60

    f32x4 st[8];  // 4 k-rows x {re, im}

    auto LOADS = [&](int t) {
        const int k0 = khbase + t * 64;
        #pragma unroll
        for (int j = 0; j < 4; ++j) {
            const size_t ro = (size_t)(k0 + kq * 4 + j) * D_DIM;
            st[j]     = ld4g(Bre + ro, d0 + ds, D_DIM);
            st[4 + j] = ld4g(Bim + ro, d0 + ds, D_DIM);
        }
    };

    auto WRITE = [&](int buf) {
        #pragma unroll
        for (int i = 0; i < 4; ++i) {
            *(uint2*)&sT[buf][0][ds + i][kq * 4] =
                make_uint2(pk(st[0][i], st[1][i]), pk(st[2][i], st[3][i]));
            *(uint2*)&sT[buf][1][ds + i][kq * 4] =
                make_uint2(pk(st[4][i], st[5][i]), pk(st[6][i], st[7][i]));
        }
    };

    const int m0  = (w & 1) * 32;     // b quadrant
    const int nl0 = (w >> 1) * 32;    // local d quadrant

    f32x4 accRe[2][2] = {};
    f32x4 accIm[2][2] = {};

    auto COMPUTE = [&](int t, int buf) {
        const int k0 = khbase + t * 64;
        uint4 aRe[2][2], aIm[2][2];
        #pragma unroll
        for (int ms = 0; ms < 2; ++ms) {
            const size_t rowo = (size_t)(m0 + ms * 16 + r) * K_DIM;
            #pragma unroll
            for (int kk = 0; kk < 2; ++kk) {
                aRe[ms][kk] = *(const uint4*)&CreBf[rowo + k0 + kk * 32 + g * 8];
                aIm[ms][kk] = *(const uint4*)&CimBf[rowo + k0 + kk * 32 + g * 8];
            }
        }
        #pragma unroll
        for (int kk = 0; kk < 2; ++kk) {
            uint4 bre[2], bim[2];
            #pragma unroll
            for (int ns = 0; ns < 2; ++ns) {
                bre[ns] = *(const uint4*)&sT[buf][0][nl0 + ns * 16 + r][kk * 32 + g * 8];
                bim[ns] = *(const uint4*)&sT[buf][1][nl0 + ns * 16 + r][kk * 32 + g * 8];
            }
            #pragma unroll
            for (int ms = 0; ms < 2; ++ms)
            #pragma unroll
            for (int ns = 0; ns < 2; ++ns) {
                // out_re += cre*Bre - cim*Bim ; out_im += cre*Bim + cim*Bre
                accRe[ms][ns] = mfma16(asbf(aRe[ms][kk]), asbf(bre[ns]), accRe[ms][ns]);
                accRe[ms][ns] = mfma16(asbf(neg4(aIm[ms][kk])), asbf(bim[ns]), accRe[ms][ns]);
                if (WIM) {
                    accIm[ms][ns] = mfma16(asbf(aRe[ms][kk]), asbf(bim[ns]), accIm[ms][ns]);
                    accIm[ms][ns] = mfma16(asbf(aIm[ms][kk]), asbf(bre[ns]), accIm[ms][ns]);
                }
            }
        }
    };

    const int NT = (K_DIM / 2) / 64;  // 16
    LOADS(0); WRITE(0); __syncthreads();
    for (int t = 0; t < NT; ++t) {
        if (t + 1 < NT) LOADS(t + 1);
        COMPUTE(t, t & 1);
        if (t + 1 < NT) WRITE((t + 1) & 1);
        __syncthreads();
    }

    #pragma unroll
    for (int ms = 0; ms < 2; ++ms)
    #pragma unroll
    for (int ns = 0; ns < 2; ++ns) {
        const int d = d0 + nl0 + ns * 16 + r;
        if (d < D_DIM) {
            #pragma unroll
            for (int i = 0; i < 4; ++i) {
                const int b = m0 + ms * 16 + g * 4 + i;
                if (!WIM) {
                    atomicAdd(&out[(size_t)b * D_DIM + d], accRe[ms][ns][i]);
                } else {
                    atomicAdd(&out[((size_t)b * D_DIM + d) * 2],     accRe[ms][ns][i]);
                    atomicAdd(&out[((size_t)b * D_DIM + d) * 2 + 1], accIm[ms][ns][i]);
                }
            }
        }
    }
}

extern "C" void kernel_launch(void* const* d_in, const int* in_sizes, int n_in,
                              void* d_out, int out_size, void* d_ws, size_t ws_size,
                              hipStream_t stream) {
    const float* Xre = (const float*)d_in[0];
    const float* Xim = (const float*)d_in[1];
    const float* Bre = (const float*)d_in[2];
    const float* Bim = (const float*)d_in[3];
    const float* Wre = (const float*)d_in[4];
    const float* Wim = (const float*)d_in[5];

    float*  Cre   = (float*)d_ws;                          // 512 KB
    float*  Cim   = Cre + B_DIM * K_DIM;                   // 512 KB
    __bf16* CreBf = (__bf16*)(Cim + B_DIM * K_DIM);        // 256 KB
    __bf16* CimBf = CreBf + B_DIM * K_DIM;                 // 256 KB
    __bf16* XreB  = CimBf + B_DIM * K_DIM;                 // 4.15 MB
    __bf16* XimB  = XreB + (size_t)B_DIM * D_DIM;          // 4.15 MB

    const size_t need = (size_t)2 * B_DIM * K_DIM * sizeof(float)
                      + (size_t)2 * B_DIM * K_DIM * sizeof(__bf16)
                      + (size_t)2 * B_DIM * D_DIM * sizeof(__bf16);
    const bool xbf = ws_size >= need;

    (void)hipMemsetAsync(d_ws, 0, (size_t)2 * B_DIM * K_DIM * sizeof(float), stream);
    (void)hipMemsetAsync(d_out, 0, (size_t)out_size * sizeof(float), stream);

    dim3 g1(K_DIM / KTILE, 32);  // x = k-group (drives XCD assignment), y = d-chunk
    if (xbf) {
        xbf_kernel<<<(B_DIM * D_DIM / 4 + 255) / 256, 256, 0, stream>>>(Xre, Xim, XreB, XimB);
        p1_coeffs<true><<<g1, 256, 0, stream>>>(Xre, Xim, XreB, XimB, Bre, Bim, Wre, Wim, Cre, Cim);
    } else {
        p1_coeffs<false><<<g1, 256, 0, stream>>>(Xre, Xim, XreB, XimB, Bre, Bim, Wre, Wim, Cre, Cim);
    }

    cbf_kernel<<<(B_DIM * K_DIM + 255) / 256, 256, 0, stream>>>(Cre, Cim, CreBf, CimBf);

    const int ndt = (D_DIM + 63) / 64;  // 507
    dim3 g2(ndt, 2);
    if (out_size == 2 * B_DIM * D_DIM) {
        p2_project<true><<<g2, 256, 0, stream>>>(Bre, Bim, CreBf, CimBf, (float*)d_out);
    } else {
        p2_project<false><<<g2, 256, 0, stream>>>(Bre, Bim, CreBf, CimBf, (float*)d_out);
    }
}